// Round 1
// 1588.218 us; speedup vs baseline: 2.0682x; 2.0682x over previous
//
#include <hip/hip_runtime.h>
#include <math.h>

#define NUM_K 4096
#define DIM   256
#define TLEN  1024
#define DT    (DIM * TLEN)     // 262144, per-batch z stride
#define CAP   2048             // candidate list capacity (expected ~75/block)

typedef short bf16x8 __attribute__((ext_vector_type(8)));   // 8 bf16 in 4 VGPRs
typedef float f32x4  __attribute__((ext_vector_type(4)));

// float -> bf16, round-to-nearest-even (bit trick; inputs finite)
static __device__ __forceinline__ unsigned short f2bf(float x) {
  unsigned u = __float_as_uint(x);
  u += 0x7fffu + ((u >> 16) & 1u);
  return (unsigned short)(u >> 16);
}

static __device__ __forceinline__ f32x4 mfma16(bf16x8 a, bf16x8 b, f32x4 c) {
  return __builtin_amdgcn_mfma_f32_16x16x32_bf16(a, b, c, 0, 0, 0);
}

// ---------------- K1a: per-code norms m_c = max(||w_c||, 1e-6), numpy-bitwise ----------------
// np.sum pairwise scheme for n=256: two 128-blocks, 8 accumulator chains each
// (plain adds, NO FMA), combined ((r0+r1)+(r2+r3))+((r4+r5)+(r6+r7)); blocks last.
// These m_c feed the EXACT rescore divisions, so the chain must stay bitwise-numpy.
__global__ __launch_bounds__(256) void wnorm_kernel(const float* __restrict__ w,
                                                    float* __restrict__ wnorms) {
  const int k = blockIdx.x * 256 + threadIdx.x;
  const float* row = w + (size_t)k * DIM;
  float p[2];
#pragma unroll
  for (int blk = 0; blk < 2; ++blk) {
    const float* b = row + blk * 128;
    float r[8];
#pragma unroll
    for (int j = 0; j < 8; ++j) r[j] = __fmul_rn(b[j], b[j]);
    for (int i = 8; i < 128; i += 8) {
#pragma unroll
      for (int j = 0; j < 8; ++j) r[j] = __fadd_rn(r[j], __fmul_rn(b[i + j], b[i + j]));
    }
    p[blk] = __fadd_rn(__fadd_rn(__fadd_rn(r[0], r[1]), __fadd_rn(r[2], r[3])),
                       __fadd_rn(__fadd_rn(r[4], r[5]), __fadd_rn(r[6], r[7])));
  }
  wnorms[k] = fmaxf(__fsqrt_rn(__fadd_rn(p[0], p[1])), 1e-6f);
}

// ---------------- K1b: bf16 B-fragment image of wn = w/m ----------------
// Image layout: fragid = chunk*32 + kb*4 + jg  (chunk of 64 codes, kb = K-block of 32
// dims, jg = 16-code column group). Each fragment is 1 KB = 64 lanes x 16 B holding
// B[k = (lane>>4)*8 + u][col = jg*16 + (lane&15)] for the 16x16x32 bf16 MFMA.
// Main kernel loads a whole fragment with one lane-contiguous global dwordx4.
__global__ __launch_bounds__(256) void wfrag_kernel(const float* __restrict__ w,
                                                    const float* __restrict__ wnorms,
                                                    unsigned short* __restrict__ img) {
  const int t = blockIdx.x * 256 + threadIdx.x;       // 512 blocks -> 131072 threads
  const int lane = t & 63;
  const int fragid = t >> 6;                           // 0..2047
  const int jg = fragid & 3;
  const int kb = (fragid >> 2) & 7;
  const int chunk = fragid >> 5;
  const int c  = (chunk << 6) + (jg << 4) + (lane & 15);
  const int d0 = (kb << 5) + ((lane >> 4) << 3);
  const float m = wnorms[c];
  const float* src = w + (size_t)c * DIM + d0;
  union { bf16x8 v; unsigned short u[8]; } o;
#pragma unroll
  for (int u = 0; u < 8; ++u) o.u[u] = f2bf(__fdiv_rn(src[u], m));
  *reinterpret_cast<bf16x8*>(img + (size_t)fragid * 512 + lane * 8) = o.v;
}

// ---------------- K2: main fused kernel (MFMA scoring + exact-chain verdict) ----------------
// grid 1024: block = (batch bb, 64-token slab t0), 4 waves: wr = token half, wc = code half.
// Scale-invariance: argmax_c zn.wn == argmax_c (z_raw . wn), so the approx pass scores
// RAW z in bf16. Certified window: |bf16dot - truedot| <= m_t*2^-8 (Cauchy-Schwarz,
// ||wn||=1); window 0.02*m_t = 2.56x the 2-sided worst-case bound, so the exact argmax
// is ALWAYS among collected candidates. Verdict on candidates = the harness's numpy
// fp32 path: zn = fdiv(z,m), wn = fdiv(w,mc), single seq FMA chain d ascending,
// first-occurrence ties -> bit-identical verdict values to the previous kernel.
__global__ __launch_bounds__(256, 3) void vq_main_kernel(
    const float* __restrict__ z, const float* __restrict__ weight,
    const unsigned short* __restrict__ wimg, const float* __restrict__ wnorms,
    float* __restrict__ out_q, float* __restrict__ out_codes,
    float* __restrict__ counts, float* __restrict__ dw,
    float* __restrict__ loss_accum) {
  __shared__ float tnorm[64];
  __shared__ float v1p[2][64];
  __shared__ float thr[64];
  __shared__ int   fidx[64];
  __shared__ int   clist[CAP];
  __shared__ float cscore[CAP];
  __shared__ int   ccount;

  const int tid  = threadIdx.x;
  const int bb   = blockIdx.x >> 4;
  const int t0   = (blockIdx.x & 15) << 6;
  const int lane = tid & 63;
  const int wv   = tid >> 6;         // wave 0..3
  const int wr   = wv >> 1;          // token half (32 tokens)
  const int wc   = wv & 1;           // code half within a 64-code chunk
  const float* zb = z + (size_t)bb * DT + t0;

  // ---- A-fragments: raw z -> bf16, held in registers for BOTH passes (64 VGPR) ----
  // A[row = lane&15][k = (lane>>4)*8 + u]; row -> token wr*32 + i*16 + (lane&15).
  bf16x8 afr[2][8];
  {
    const int tloc = (wr << 5) + (lane & 15);
    const int dr   = (lane >> 4) << 3;
#pragma unroll
    for (int i = 0; i < 2; ++i) {
      const float* zc = zb + tloc + (i << 4);
#pragma unroll
      for (int kb = 0; kb < 8; ++kb) {
        union { bf16x8 v; unsigned short u[8]; } a;
#pragma unroll
        for (int u = 0; u < 8; ++u)
          a.u[u] = f2bf(zc[(size_t)((kb << 5) + dr + u) * TLEN]);
        afr[i][kb] = a.v;
      }
    }
  }

  // ---- per-token norms, numpy-bitwise pairwise scheme (coalesced global re-read) ----
  if (tid < 64) {
    const float* zc = zb + tid;
    float p[2];
#pragma unroll
    for (int blk = 0; blk < 2; ++blk) {
      float r[8];
#pragma unroll
      for (int j = 0; j < 8; ++j) {
        const float v = zc[(size_t)(blk * 128 + j) * TLEN];
        r[j] = __fmul_rn(v, v);
      }
      for (int i = 8; i < 128; i += 8) {
#pragma unroll
        for (int j = 0; j < 8; ++j) {
          const float v = zc[(size_t)(blk * 128 + i + j) * TLEN];
          r[j] = __fadd_rn(r[j], __fmul_rn(v, v));
        }
      }
      p[blk] = __fadd_rn(__fadd_rn(__fadd_rn(r[0], r[1]), __fadd_rn(r[2], r[3])),
                         __fadd_rn(__fadd_rn(r[4], r[5]), __fadd_rn(r[6], r[7])));
    }
    tnorm[tid] = fmaxf(__fsqrt_rn(__fadd_rn(p[0], p[1])), 1e-6f);
  }
  if (tid == 0) ccount = 0;

  const unsigned short* bbase = wimg + (wc << 10) + (lane << 3);
  const f32x4 zero4 = {0.f, 0.f, 0.f, 0.f};

  // ---- PASS A: approx max per token (code 0 masked out) ----
  float v1loc[2][4];
#pragma unroll
  for (int i = 0; i < 2; ++i)
#pragma unroll
    for (int r = 0; r < 4; ++r) v1loc[i][r] = -INFINITY;
  {
    const bool lc0 = (wc == 0) && ((lane & 15) == 0);   // lane carrying code chunk*64+0
#pragma unroll 2
    for (int chunk = 0; chunk < 64; ++chunk) {
      const unsigned short* bc_ = bbase + ((size_t)chunk << 14);
      f32x4 acc[2][2];
      acc[0][0] = zero4; acc[0][1] = zero4; acc[1][0] = zero4; acc[1][1] = zero4;
#pragma unroll
      for (int kb = 0; kb < 8; ++kb) {
        const bf16x8 b0 = *reinterpret_cast<const bf16x8*>(bc_ + (kb << 11));
        const bf16x8 b1 = *reinterpret_cast<const bf16x8*>(bc_ + (kb << 11) + 512);
        acc[0][0] = mfma16(afr[0][kb], b0, acc[0][0]);
        acc[1][0] = mfma16(afr[1][kb], b0, acc[1][0]);
        acc[0][1] = mfma16(afr[0][kb], b1, acc[0][1]);
        acc[1][1] = mfma16(afr[1][kb], b1, acc[1][1]);
      }
#pragma unroll
      for (int i = 0; i < 2; ++i)
#pragma unroll
        for (int r = 0; r < 4; ++r) {
          float v0 = acc[i][0][r];
          if (chunk == 0 && lc0) v0 = -INFINITY;        // exclude reserved code 0
          v1loc[i][r] = fmaxf(v1loc[i][r], fmaxf(v0, acc[i][1][r]));
        }
    }
  }
  // cross-lane reduce over the 16 code-columns, then across wc halves via LDS
#pragma unroll
  for (int i = 0; i < 2; ++i)
#pragma unroll
    for (int r = 0; r < 4; ++r) {
      float v = v1loc[i][r];
      v = fmaxf(v, __shfl_xor(v, 1));
      v = fmaxf(v, __shfl_xor(v, 2));
      v = fmaxf(v, __shfl_xor(v, 4));
      v = fmaxf(v, __shfl_xor(v, 8));
      if ((lane & 15) == 0)
        v1p[wc][(wr << 5) + (i << 4) + ((lane >> 4) << 2) + r] = v;
    }
  __syncthreads();
  // window = 0.02*m_t (>= 2.56x certified 2-sided bf16 error bound of 2*m_t*2^-8)
  if (tid < 64) thr[tid] = fmaxf(v1p[0][tid], v1p[1][tid]) - 0.02f * tnorm[tid];
  __syncthreads();

  float thrv_[2][4];
  {
    const int tb = (wr << 5) + ((lane >> 4) << 2);
#pragma unroll
    for (int i = 0; i < 2; ++i)
#pragma unroll
      for (int r = 0; r < 4; ++r) thrv_[i][r] = thr[tb + (i << 4) + r];
  }

  // ---- PASS B: bitwise-identical recompute, collect candidates >= threshold ----
  {
#pragma unroll 2
    for (int chunk = 0; chunk < 64; ++chunk) {
      const unsigned short* bc_ = bbase + ((size_t)chunk << 14);
      f32x4 acc[2][2];
      acc[0][0] = zero4; acc[0][1] = zero4; acc[1][0] = zero4; acc[1][1] = zero4;
#pragma unroll
      for (int kb = 0; kb < 8; ++kb) {
        const bf16x8 b0 = *reinterpret_cast<const bf16x8*>(bc_ + (kb << 11));
        const bf16x8 b1 = *reinterpret_cast<const bf16x8*>(bc_ + (kb << 11) + 512);
        acc[0][0] = mfma16(afr[0][kb], b0, acc[0][0]);
        acc[1][0] = mfma16(afr[1][kb], b0, acc[1][0]);
        acc[0][1] = mfma16(afr[0][kb], b1, acc[0][1]);
        acc[1][1] = mfma16(afr[1][kb], b1, acc[1][1]);
      }
#pragma unroll
      for (int i = 0; i < 2; ++i)
#pragma unroll
        for (int j = 0; j < 2; ++j) {
          const int c = (chunk << 6) + (wc << 5) + (j << 4) + (lane & 15);
#pragma unroll
          for (int r = 0; r < 4; ++r) {
            if (acc[i][j][r] >= thrv_[i][r] && c != 0) {
              const int pos = atomicAdd(&ccount, 1);
              if (pos < CAP)
                clist[pos] = (c << 7) | ((wr << 5) + (i << 4) + ((lane >> 4) << 2) + r);
            }
          }
        }
    }
  }
  __syncthreads();

  // ---- exact numpy-fp32 seq-FMA rescore of candidates (the verdict) ----
  const int ncand = min(ccount, CAP);
  for (int e = tid; e < ncand; e += 256) {
    const int pk = clist[e];
    const int tloc = pk & 127;
    const int c = pk >> 7;
    const float m  = tnorm[tloc];
    const float mc = wnorms[c];
    const float* zc = zb + tloc;
    const float* wp = weight + (size_t)c * DIM;
    float s = 0.f;
#pragma unroll 8
    for (int d = 0; d < DIM; ++d)
      s = fmaf(__fdiv_rn(zc[(size_t)d * TLEN], m), __fdiv_rn(wp[d], mc), s);
    cscore[e] = s;
  }
  __syncthreads();

  // ---- per-token select: max exact score, first occurrence (lower index) on ties ----
  if (tid < 64) {
    float best = -INFINITY; int bc = NUM_K;
    for (int e = 0; e < ncand; ++e) {
      const int pk = clist[e];
      if ((pk & 127) == tid) {
        const float s = cscore[e]; const int c = pk >> 7;
        if (s > best || (s == best && c < bc)) { best = s; bc = c; }
      }
    }
    if (bc >= NUM_K) bc = 1;   // unreachable guard (every token's max is collected)
    fidx[tid] = bc;
    out_codes[bb * TLEN + t0 + tid] = (float)bc;
    atomicAdd(&counts[bc], 1.0f);
  }
  __syncthreads();

  // ---- output phase: quantized = weight[idx] (raw), loss vs raw z, dw = sum(zn) ----
  {
    const int qv = tid >> 6, ln = tid & 63;
    const int code = fidx[ln];
    const float m = tnorm[ln];
    const float* wrow = weight + (size_t)code * DIM;
    const float* zcol = zb + ln;
    float* qbase = out_q + (size_t)bb * DT + t0 + ln;
    float* dwrow = dw + (size_t)code * DIM;
    float lpart = 0.f;
#pragma unroll 4
    for (int dd = 0; dd < 64; ++dd) {
      const int d = (qv << 6) + dd;
      const float wval = wrow[d];                  // L2-hot gather
      const float zval = zcol[(size_t)d * TLEN];   // coalesced over lanes
      qbase[(size_t)d * TLEN] = wval;
      const float df = wval - zval;                // exact raw-z difference
      lpart = fmaf(df, df, lpart);
      atomicAdd(&dwrow[d], __fdiv_rn(zval, m));    // dw = segment_sum(flat_z_norm)
    }
#pragma unroll
    for (int off = 32; off; off >>= 1) lpart += __shfl_down(lpart, off, 64);
    if (ln == 0) atomicAdd(loss_accum, lpart);
  }
}

// ---------------- K3: new_cs, n, loss scalar ----------------
__global__ __launch_bounds__(256) void finalize_cs_kernel(
    const float* __restrict__ counts, const float* __restrict__ ema_cs,
    float* __restrict__ out_ncs, float* __restrict__ ws_n,
    const float* __restrict__ loss_accum, float* __restrict__ out_loss) {
  __shared__ float red[4];
  const int tid = threadIdx.x;
  float part = 0.f;
  for (int k = tid; k < NUM_K; k += 256) {
    const float v = (k == 0) ? 0.f : 0.99f * ema_cs[k] + 0.01f * counts[k];
    out_ncs[k] = v;
    part += v;
  }
#pragma unroll
  for (int off = 32; off; off >>= 1) part += __shfl_down(part, off, 64);
  if ((tid & 63) == 0) red[tid >> 6] = part;
  __syncthreads();
  if (tid == 0) {
    ws_n[0] = red[0] + red[1] + red[2] + red[3];
    out_loss[0] = 0.25f * loss_accum[0] / 16777216.0f;  // mean over B*T*D
  }
}

// ---------------- K4: new_ema_w (in place over dw) + new_weight ----------------
__global__ __launch_bounds__(256) void finalize_w_kernel(
    const float* __restrict__ ema_w, const float* __restrict__ ncs,
    const float* __restrict__ ws_n, float* __restrict__ new_ema_w,
    float* __restrict__ new_weight) {
  const int wid  = threadIdx.x >> 6;
  const int lane = threadIdx.x & 63;
  const int k    = (blockIdx.x << 2) + wid;
  const float n  = ws_n[0];
  const float cs = (ncs[k] + 1e-5f) / (n + 4096.0f * 1e-5f) * n;
  const float* erow = ema_w + k * DIM;
  float* nrow = new_ema_w + k * DIM;
  float* wrow = new_weight + k * DIM;
  const int d0 = lane << 2;
  float u[4]; float ss = 0.f;
#pragma unroll
  for (int j = 0; j < 4; ++j) {
    const float dwv = nrow[d0 + j];
    const float val = (k == 0) ? 0.f : 0.99f * erow[d0 + j] + 0.01f * dwv;
    nrow[d0 + j] = val;
    const float uu = val / cs;
    u[j] = uu;
    ss = fmaf(uu, uu, ss);
  }
#pragma unroll
  for (int off = 32; off; off >>= 1) ss += __shfl_xor(ss, off, 64);
  const float m = fmaxf(sqrtf(ss), 1e-6f);
#pragma unroll
  for (int j = 0; j < 4; ++j) wrow[d0 + j] = u[j] / m;
}

extern "C" void kernel_launch(void* const* d_in, const int* in_sizes, int n_in,
                              void* d_out, int out_size, void* d_ws, size_t ws_size,
                              hipStream_t stream) {
  const float* z      = (const float*)d_in[0];   // [64,256,1024]
  const float* weight = (const float*)d_in[1];   // [4096,256]
  const float* ema_cs = (const float*)d_in[2];   // [4096]
  const float* ema_w  = (const float*)d_in[3];   // [4096,256]

  float* out = (float*)d_out;
  // output layout (floats): quantized | loss | codes | new_weight | new_cs | new_ema_w
  float* out_q     = out;                    // 16777216
  float* out_loss  = out + 16777216;         // 1
  float* out_codes = out + 16777217;         // 65536
  float* out_nw    = out + 16842753;         // 1048576 (first 2 MiB: temp bf16 B-frag image)
  float* out_ncs   = out + 17891329;         // 4096
  float* out_new   = out + 17895425;         // 1048576 (dw accumulates here, then in-place)

  float* counts     = (float*)d_ws;          // 4096 floats
  float* loss_accum = counts + 4096;         // 1
  float* ws_n       = counts + 4097;         // 1
  float* wnorms     = counts + 4352;         // 4096 floats, 16B-aligned (ws use: 33.8 KB)

  // out_nw is only 4B-aligned (odd float offset); +3 floats makes the image 16B-aligned.
  unsigned short* wimg = (unsigned short*)(out_nw + 3);   // 2 MiB, overwritten by K4 later

  hipMemsetAsync(d_ws, 0, 4098 * sizeof(float), stream);
  hipMemsetAsync(out_new, 0, (size_t)NUM_K * DIM * sizeof(float), stream);

  wnorm_kernel<<<16, 256, 0, stream>>>(weight, wnorms);
  wfrag_kernel<<<512, 256, 0, stream>>>(weight, wnorms, wimg);
  vq_main_kernel<<<1024, 256, 0, stream>>>(z, weight, wimg, wnorms, out_q, out_codes,
                                           counts, out_new, loss_accum);
  finalize_cs_kernel<<<1, 256, 0, stream>>>(counts, ema_cs, out_ncs, ws_n,
                                            loss_accum, out_loss);
  finalize_w_kernel<<<NUM_K / 4, 256, 0, stream>>>(ema_w, out_ncs, ws_n,
                                                   out_new, out_nw);
}

// Round 2
// 864.364 us; speedup vs baseline: 3.8001x; 1.8374x over previous
//
#include <hip/hip_runtime.h>
#include <math.h>

#define NUM_K 4096
#define DIM   256
#define TLEN  1024
#define DT    (DIM * TLEN)     // 262144, per-batch z stride
#define CAP   2048             // candidate list capacity (expected ~450/block)

typedef short bf16x8 __attribute__((ext_vector_type(8)));   // 8 bf16 in 4 VGPRs
typedef float f32x4  __attribute__((ext_vector_type(4)));

// float -> bf16, round-to-nearest-even (bit trick; inputs finite)
static __device__ __forceinline__ unsigned short f2bf(float x) {
  unsigned u = __float_as_uint(x);
  u += 0x7fffu + ((u >> 16) & 1u);
  return (unsigned short)(u >> 16);
}

static __device__ __forceinline__ f32x4 mfma16(bf16x8 a, bf16x8 b, f32x4 c) {
  return __builtin_amdgcn_mfma_f32_16x16x32_bf16(a, b, c, 0, 0, 0);
}

// ---------------- K1a: per-code norms m_c = max(||w_c||, 1e-6), numpy-bitwise ----------------
__global__ __launch_bounds__(256) void wnorm_kernel(const float* __restrict__ w,
                                                    float* __restrict__ wnorms) {
  const int k = blockIdx.x * 256 + threadIdx.x;
  const float* row = w + (size_t)k * DIM;
  float p[2];
#pragma unroll
  for (int blk = 0; blk < 2; ++blk) {
    const float* b = row + blk * 128;
    float r[8];
#pragma unroll
    for (int j = 0; j < 8; ++j) r[j] = __fmul_rn(b[j], b[j]);
    for (int i = 8; i < 128; i += 8) {
#pragma unroll
      for (int j = 0; j < 8; ++j) r[j] = __fadd_rn(r[j], __fmul_rn(b[i + j], b[i + j]));
    }
    p[blk] = __fadd_rn(__fadd_rn(__fadd_rn(r[0], r[1]), __fadd_rn(r[2], r[3])),
                       __fadd_rn(__fadd_rn(r[4], r[5]), __fadd_rn(r[6], r[7])));
  }
  wnorms[k] = fmaxf(__fsqrt_rn(__fadd_rn(p[0], p[1])), 1e-6f);
}

// ---------------- K1b: bf16 B-fragment image of wn = w/m ----------------
// fragid = chunk*32 + kb*4 + jg; each fragment 1 KB = 64 lanes x 16 B:
// B[k = (lane>>4)*8 + u][col = jg*16 + (lane&15)] for mfma 16x16x32 bf16.
__global__ __launch_bounds__(256) void wfrag_kernel(const float* __restrict__ w,
                                                    const float* __restrict__ wnorms,
                                                    unsigned short* __restrict__ img) {
  const int t = blockIdx.x * 256 + threadIdx.x;
  const int lane = t & 63;
  const int fragid = t >> 6;                           // 0..2047
  const int jg = fragid & 3;
  const int kb = (fragid >> 2) & 7;
  const int chunk = fragid >> 5;
  const int c  = (chunk << 6) + (jg << 4) + (lane & 15);
  const int d0 = (kb << 5) + ((lane >> 4) << 3);
  const float m = wnorms[c];
  const float* src = w + (size_t)c * DIM + d0;
  union { bf16x8 v; unsigned short u[8]; } o;
#pragma unroll
  for (int u = 0; u < 8; ++u) o.u[u] = f2bf(__fdiv_rn(src[u], m));
  *reinterpret_cast<bf16x8*>(img + (size_t)fragid * 512 + lane * 8) = o.v;
}

// ---------------- K2: main fused kernel (MFMA scoring + exact-chain verdict) ----------------
// Changes vs prev round: (1) NO global dw atomics — writes znT (= flat_z_norm,
// token-major, coalesced) into the out_q region instead; dw is computed later by a
// bucketed reduction. (2) B fragments batched 16-at-a-time into registers per chunk
// (one latency stall per chunk instead of 8). (3) s_setprio(1) around the MFMA
// cluster (barrier-free independent waves — the regime where setprio pays).
// Verdict math unchanged: bf16-MFMA approx scan, certified window 0.02*m_t
// (2.56x the worst-case bf16 dot error bound), exact numpy fp32 seq-FMA rescore.
__global__ __launch_bounds__(256, 3) void vq_main_kernel(
    const float* __restrict__ z, const float* __restrict__ weight,
    const unsigned short* __restrict__ wimg, const float* __restrict__ wnorms,
    float* __restrict__ znT, float* __restrict__ out_codes,
    float* __restrict__ counts, float* __restrict__ loss_accum) {
  __shared__ float tnorm[64];
  __shared__ float v1p[2][64];
  __shared__ float thr[64];
  __shared__ int   fidx[64];
  __shared__ int   clist[CAP];
  __shared__ float cscore[CAP];
  __shared__ int   ccount;

  const int tid  = threadIdx.x;
  const int bb   = blockIdx.x >> 4;
  const int t0   = (blockIdx.x & 15) << 6;
  const int lane = tid & 63;
  const int wv   = tid >> 6;         // wave 0..3
  const int wr   = wv >> 1;          // token half (32 tokens)
  const int wc   = wv & 1;           // code half within a 64-code chunk
  const float* zb = z + (size_t)bb * DT + t0;

  // ---- A-fragments: raw z -> bf16, held in registers for BOTH passes (64 VGPR) ----
  bf16x8 afr[2][8];
  {
    const int tloc = (wr << 5) + (lane & 15);
    const int dr   = (lane >> 4) << 3;
#pragma unroll
    for (int i = 0; i < 2; ++i) {
      const float* zc = zb + tloc + (i << 4);
#pragma unroll
      for (int kb = 0; kb < 8; ++kb) {
        union { bf16x8 v; unsigned short u[8]; } a;
#pragma unroll
        for (int u = 0; u < 8; ++u)
          a.u[u] = f2bf(zc[(size_t)((kb << 5) + dr + u) * TLEN]);
        afr[i][kb] = a.v;
      }
    }
  }

  // ---- per-token norms, numpy-bitwise pairwise scheme ----
  if (tid < 64) {
    const float* zc = zb + tid;
    float p[2];
#pragma unroll
    for (int blk = 0; blk < 2; ++blk) {
      float r[8];
#pragma unroll
      for (int j = 0; j < 8; ++j) {
        const float v = zc[(size_t)(blk * 128 + j) * TLEN];
        r[j] = __fmul_rn(v, v);
      }
      for (int i = 8; i < 128; i += 8) {
#pragma unroll
        for (int j = 0; j < 8; ++j) {
          const float v = zc[(size_t)(blk * 128 + i + j) * TLEN];
          r[j] = __fadd_rn(r[j], __fmul_rn(v, v));
        }
      }
      p[blk] = __fadd_rn(__fadd_rn(__fadd_rn(r[0], r[1]), __fadd_rn(r[2], r[3])),
                         __fadd_rn(__fadd_rn(r[4], r[5]), __fadd_rn(r[6], r[7])));
    }
    tnorm[tid] = fmaxf(__fsqrt_rn(__fadd_rn(p[0], p[1])), 1e-6f);
  }
  if (tid == 0) ccount = 0;

  const unsigned short* bbase = wimg + (wc << 10) + (lane << 3);
  const f32x4 zero4 = {0.f, 0.f, 0.f, 0.f};

  // ---- PASS A: approx max per token (code 0 masked out) ----
  float v1loc[2][4];
#pragma unroll
  for (int i = 0; i < 2; ++i)
#pragma unroll
    for (int r = 0; r < 4; ++r) v1loc[i][r] = -INFINITY;
  {
    const bool lc0 = (wc == 0) && ((lane & 15) == 0);
#pragma unroll 1
    for (int chunk = 0; chunk < 64; ++chunk) {
      const unsigned short* bc_ = bbase + ((size_t)chunk << 14);
      bf16x8 bf[16];                          // batch all 16 fragment loads
#pragma unroll
      for (int kb = 0; kb < 8; ++kb) {
        bf[kb]     = *reinterpret_cast<const bf16x8*>(bc_ + (kb << 11));
        bf[kb + 8] = *reinterpret_cast<const bf16x8*>(bc_ + (kb << 11) + 512);
      }
      f32x4 acc[2][2];
      acc[0][0] = zero4; acc[0][1] = zero4; acc[1][0] = zero4; acc[1][1] = zero4;
      __builtin_amdgcn_s_setprio(1);
#pragma unroll
      for (int kb = 0; kb < 8; ++kb) {
        acc[0][0] = mfma16(afr[0][kb], bf[kb],     acc[0][0]);
        acc[1][0] = mfma16(afr[1][kb], bf[kb],     acc[1][0]);
        acc[0][1] = mfma16(afr[0][kb], bf[kb + 8], acc[0][1]);
        acc[1][1] = mfma16(afr[1][kb], bf[kb + 8], acc[1][1]);
      }
      __builtin_amdgcn_s_setprio(0);
#pragma unroll
      for (int i = 0; i < 2; ++i)
#pragma unroll
        for (int r = 0; r < 4; ++r) {
          float v0 = acc[i][0][r];
          if (chunk == 0 && lc0) v0 = -INFINITY;
          v1loc[i][r] = fmaxf(v1loc[i][r], fmaxf(v0, acc[i][1][r]));
        }
    }
  }
#pragma unroll
  for (int i = 0; i < 2; ++i)
#pragma unroll
    for (int r = 0; r < 4; ++r) {
      float v = v1loc[i][r];
      v = fmaxf(v, __shfl_xor(v, 1));
      v = fmaxf(v, __shfl_xor(v, 2));
      v = fmaxf(v, __shfl_xor(v, 4));
      v = fmaxf(v, __shfl_xor(v, 8));
      if ((lane & 15) == 0)
        v1p[wc][(wr << 5) + (i << 4) + ((lane >> 4) << 2) + r] = v;
    }
  __syncthreads();
  if (tid < 64) thr[tid] = fmaxf(v1p[0][tid], v1p[1][tid]) - 0.02f * tnorm[tid];
  __syncthreads();

  float thrv_[2][4];
  {
    const int tb = (wr << 5) + ((lane >> 4) << 2);
#pragma unroll
    for (int i = 0; i < 2; ++i)
#pragma unroll
      for (int r = 0; r < 4; ++r) thrv_[i][r] = thr[tb + (i << 4) + r];
  }

  // ---- PASS B: bitwise-identical recompute, collect candidates >= threshold ----
  {
#pragma unroll 1
    for (int chunk = 0; chunk < 64; ++chunk) {
      const unsigned short* bc_ = bbase + ((size_t)chunk << 14);
      bf16x8 bf[16];
#pragma unroll
      for (int kb = 0; kb < 8; ++kb) {
        bf[kb]     = *reinterpret_cast<const bf16x8*>(bc_ + (kb << 11));
        bf[kb + 8] = *reinterpret_cast<const bf16x8*>(bc_ + (kb << 11) + 512);
      }
      f32x4 acc[2][2];
      acc[0][0] = zero4; acc[0][1] = zero4; acc[1][0] = zero4; acc[1][1] = zero4;
      __builtin_amdgcn_s_setprio(1);
#pragma unroll
      for (int kb = 0; kb < 8; ++kb) {
        acc[0][0] = mfma16(afr[0][kb], bf[kb],     acc[0][0]);
        acc[1][0] = mfma16(afr[1][kb], bf[kb],     acc[1][0]);
        acc[0][1] = mfma16(afr[0][kb], bf[kb + 8], acc[0][1]);
        acc[1][1] = mfma16(afr[1][kb], bf[kb + 8], acc[1][1]);
      }
      __builtin_amdgcn_s_setprio(0);
#pragma unroll
      for (int i = 0; i < 2; ++i)
#pragma unroll
        for (int j = 0; j < 2; ++j) {
          const int c = (chunk << 6) + (wc << 5) + (j << 4) + (lane & 15);
#pragma unroll
          for (int r = 0; r < 4; ++r) {
            if (acc[i][j][r] >= thrv_[i][r] && c != 0) {
              const int pos = atomicAdd(&ccount, 1);
              if (pos < CAP)
                clist[pos] = (c << 7) | ((wr << 5) + (i << 4) + ((lane >> 4) << 2) + r);
            }
          }
        }
    }
  }
  __syncthreads();

  // ---- exact numpy-fp32 seq-FMA rescore of candidates (the verdict) ----
  const int ncand = min(ccount, CAP);
  for (int e = tid; e < ncand; e += 256) {
    const int pk = clist[e];
    const int tloc = pk & 127;
    const int c = pk >> 7;
    const float m  = tnorm[tloc];
    const float mc = wnorms[c];
    const float* zc = zb + tloc;
    const float* wp = weight + (size_t)c * DIM;
    float s = 0.f;
#pragma unroll 8
    for (int d = 0; d < DIM; ++d)
      s = fmaf(__fdiv_rn(zc[(size_t)d * TLEN], m), __fdiv_rn(wp[d], mc), s);
    cscore[e] = s;
  }
  __syncthreads();

  // ---- per-token select: max exact score, first occurrence (lower index) on ties ----
  if (tid < 64) {
    float best = -INFINITY; int bc = NUM_K;
    for (int e = 0; e < ncand; ++e) {
      const int pk = clist[e];
      if ((pk & 127) == tid) {
        const float s = cscore[e]; const int c = pk >> 7;
        if (s > best || (s == best && c < bc)) { best = s; bc = c; }
      }
    }
    if (bc >= NUM_K) bc = 1;   // unreachable guard
    fidx[tid] = bc;
    out_codes[bb * TLEN + t0 + tid] = (float)bc;
    atomicAdd(&counts[bc], 1.0f);
  }
  __syncthreads();

  // ---- output phase: znT = flat_z_norm (token-major, coalesced) + exact loss ----
  // q is NOT written here (znT occupies its region); qwrite_kernel regenerates it
  // from codes+weight after dw_kernel consumes znT.
  {
    const int gbase = (bb << 10) + t0;
    float lpart = 0.f;
#pragma unroll 4
    for (int r = 0; r < 16; ++r) {
      const int tk = (r << 2) + wv;           // one token per wave per round
      const int code = fidx[tk];
      const float m = tnorm[tk];
      const float* zc = zb + tk;
      const float4 w4 = *reinterpret_cast<const float4*>(
          weight + (size_t)code * DIM + (lane << 2));   // coalesced row read
      float4 zr4;
      zr4.x = zc[(size_t)((lane << 2) + 0) * TLEN];     // scattered, L2-hot
      zr4.y = zc[(size_t)((lane << 2) + 1) * TLEN];
      zr4.z = zc[(size_t)((lane << 2) + 2) * TLEN];
      zr4.w = zc[(size_t)((lane << 2) + 3) * TLEN];
      float4 zn4;
      zn4.x = __fdiv_rn(zr4.x, m);
      zn4.y = __fdiv_rn(zr4.y, m);
      zn4.z = __fdiv_rn(zr4.z, m);
      zn4.w = __fdiv_rn(zr4.w, m);
      *reinterpret_cast<float4*>(znT + (size_t)(gbase + tk) * DIM + (lane << 2)) = zn4;
      const float dx = w4.x - zr4.x, dy = w4.y - zr4.y;
      const float dz = w4.z - zr4.z, dw_ = w4.w - zr4.w;
      lpart = fmaf(dx, dx, lpart); lpart = fmaf(dy, dy, lpart);
      lpart = fmaf(dz, dz, lpart); lpart = fmaf(dw_, dw_, lpart);
    }
#pragma unroll
    for (int off = 32; off; off >>= 1) lpart += __shfl_down(lpart, off, 64);
    if (lane == 0) atomicAdd(loss_accum, lpart);
  }
}

// ---------------- K3: new_cs, n, loss scalar + exclusive scan of counts ----------------
__global__ __launch_bounds__(256) void finalize_cs_kernel(
    const float* __restrict__ counts, const float* __restrict__ ema_cs,
    float* __restrict__ out_ncs, float* __restrict__ ws_n,
    const float* __restrict__ loss_accum, float* __restrict__ out_loss,
    int* __restrict__ offsets) {
  __shared__ float redf[4];
  __shared__ int   redi[4];
  const int tid = threadIdx.x;
  const int lane = tid & 63, wv = tid >> 6;
  const int base = tid << 4;
  int cloc[16]; int csum = 0; float fsum = 0.f;
#pragma unroll
  for (int j = 0; j < 16; ++j) {
    const int k = base + j;
    const float cf = counts[k];
    const float v = (k == 0) ? 0.f : 0.99f * ema_cs[k] + 0.01f * cf;
    out_ncs[k] = v; fsum += v;
    cloc[j] = csum; csum += (int)cf;
  }
  int inc = csum;                    // wave-inclusive scan
#pragma unroll
  for (int off = 1; off < 64; off <<= 1) {
    const int t = __shfl_up(inc, off, 64);
    if (lane >= off) inc += t;
  }
  float fs = fsum;
#pragma unroll
  for (int off = 32; off; off >>= 1) fs += __shfl_down(fs, off, 64);
  if (lane == 63) redi[wv] = inc;
  if (lane == 0)  redf[wv] = fs;
  __syncthreads();
  int wbase = 0;
#pragma unroll
  for (int w = 0; w < 4; ++w) wbase += (w < wv) ? redi[w] : 0;
  const int tbase = wbase + inc - csum;   // exclusive base for this thread
#pragma unroll
  for (int j = 0; j < 16; ++j) offsets[base + j] = tbase + cloc[j];
  if (tid == 0) {
    ws_n[0] = redf[0] + redf[1] + redf[2] + redf[3];
    out_loss[0] = 0.25f * loss_accum[0] / 16777216.0f;
  }
}

// ---------------- K3b: scatter token ids into per-code buckets ----------------
__global__ __launch_bounds__(256) void scatter_kernel(
    const float* __restrict__ codes, const int* __restrict__ offsets,
    int* __restrict__ cursor, int* __restrict__ bucket) {
  const int g = blockIdx.x * 256 + threadIdx.x;
  const int c = (int)codes[g];
  const int pos = atomicAdd(&cursor[c], 1);
  bucket[offsets[c] + pos] = g;
}

// ---------------- K3c: dw[k] = sum of znT rows in bucket k (coalesced, no atomics) ----------------
__global__ __launch_bounds__(256) void dw_kernel(
    const float* __restrict__ znT, const float* __restrict__ counts,
    const int* __restrict__ offsets, const int* __restrict__ bucket,
    float* __restrict__ dw) {
  const int c = blockIdx.x;
  const int cnt = (int)counts[c];
  const int off = offsets[c];
  const int tid = threadIdx.x;
  float acc = 0.f;
  for (int i = 0; i < cnt; ++i) {
    const int g = bucket[off + i];
    acc += znT[(size_t)g * DIM + tid];     // 1 KB coalesced row read
  }
  dw[(size_t)c * DIM + tid] = acc;         // writes every row (memset dropped)
}

// ---------------- K4: new_ema_w (in place over dw) + new_weight ----------------
__global__ __launch_bounds__(256) void finalize_w_kernel(
    const float* __restrict__ ema_w, const float* __restrict__ ncs,
    const float* __restrict__ ws_n, float* __restrict__ new_ema_w,
    float* __restrict__ new_weight) {
  const int wid  = threadIdx.x >> 6;
  const int lane = threadIdx.x & 63;
  const int k    = (blockIdx.x << 2) + wid;
  const float n  = ws_n[0];
  const float cs = (ncs[k] + 1e-5f) / (n + 4096.0f * 1e-5f) * n;
  const float* erow = ema_w + k * DIM;
  float* nrow = new_ema_w + k * DIM;
  float* wrow = new_weight + k * DIM;
  const int d0 = lane << 2;
  float u[4]; float ss = 0.f;
#pragma unroll
  for (int j = 0; j < 4; ++j) {
    const float dwv = nrow[d0 + j];
    const float val = (k == 0) ? 0.f : 0.99f * erow[d0 + j] + 0.01f * dwv;
    nrow[d0 + j] = val;
    const float uu = val / cs;
    u[j] = uu;
    ss = fmaf(uu, uu, ss);
  }
#pragma unroll
  for (int off = 32; off; off >>= 1) ss += __shfl_xor(ss, off, 64);
  const float m = fmaxf(sqrtf(ss), 1e-6f);
#pragma unroll
  for (int j = 0; j < 4; ++j) wrow[d0 + j] = u[j] / m;
}

// ---------------- K5: final quantized = weight[idx], overwrites znT region ----------------
__global__ __launch_bounds__(256) void qwrite_kernel(
    const float* __restrict__ codes, const float* __restrict__ weight,
    float* __restrict__ out_q) {
  const int bb = blockIdx.x >> 4;
  const int t0 = (blockIdx.x & 15) << 6;
  const int ln = threadIdx.x & 63, qv = threadIdx.x >> 6;
  const int code = (int)codes[bb * TLEN + t0 + ln];
  const float* wrow = weight + (size_t)code * DIM;
  float* qb = out_q + (size_t)bb * DT + t0 + ln;
#pragma unroll 4
  for (int dd = 0; dd < 64; ++dd) {
    const int d = (qv << 6) + dd;
    qb[(size_t)d * TLEN] = wrow[d];        // gather L2-hot, store coalesced
  }
}

extern "C" void kernel_launch(void* const* d_in, const int* in_sizes, int n_in,
                              void* d_out, int out_size, void* d_ws, size_t ws_size,
                              hipStream_t stream) {
  const float* z      = (const float*)d_in[0];   // [64,256,1024]
  const float* weight = (const float*)d_in[1];   // [4096,256]
  const float* ema_cs = (const float*)d_in[2];   // [4096]
  const float* ema_w  = (const float*)d_in[3];   // [4096,256]

  float* out = (float*)d_out;
  // output layout (floats): quantized | loss | codes | new_weight | new_cs | new_ema_w
  float* out_q     = out;                    // 16777216 (holds znT until qwrite)
  float* out_loss  = out + 16777216;         // 1
  float* out_codes = out + 16777217;         // 65536
  float* out_nw    = out + 16842753;         // 1048576 (temp: wimg/bucket/offsets/cursor)
  float* out_ncs   = out + 17891329;         // 4096
  float* out_new   = out + 17895425;         // 1048576 (dw written fully by dw_kernel)

  float* counts     = (float*)d_ws;          // 4096 floats
  float* loss_accum = counts + 4096;         // 1
  float* ws_n       = counts + 4097;         // 1
  float* wnorms     = counts + 4352;         // 4096 floats, 16B-aligned

  // Scratch aliased into dead d_out regions (no new workspace needed):
  // wimg: 2 MiB bf16 image at out_nw+3 (16B-aligned); dead after vq_main.
  // bucket overlays the first 256 KB of the dead image; offsets/cursor sit past it.
  // finalize_w overwrites the whole out_nw region at the end.
  unsigned short* wimg = (unsigned short*)(out_nw + 3);
  int* bucket  = (int*)(out_nw + 3);         // 65536 ints (aliases dead wimg)
  int* offsets = (int*)(out_nw + 524292);    // 4096 ints
  int* cursor  = (int*)(out_nw + 528388);    // 4096 ints

  hipMemsetAsync(d_ws, 0, 4098 * sizeof(float), stream);
  hipMemsetAsync(cursor, 0, 4096 * sizeof(int), stream);

  wnorm_kernel<<<16, 256, 0, stream>>>(weight, wnorms);
  wfrag_kernel<<<512, 256, 0, stream>>>(weight, wnorms, wimg);
  vq_main_kernel<<<1024, 256, 0, stream>>>(z, weight, wimg, wnorms, out_q /*znT*/,
                                           out_codes, counts, loss_accum);
  finalize_cs_kernel<<<1, 256, 0, stream>>>(counts, ema_cs, out_ncs, ws_n,
                                            loss_accum, out_loss, offsets);
  scatter_kernel<<<256, 256, 0, stream>>>(out_codes, offsets, cursor, bucket);
  dw_kernel<<<NUM_K, 256, 0, stream>>>(out_q /*znT*/, counts, offsets, bucket, out_new);
  finalize_w_kernel<<<NUM_K / 4, 256, 0, stream>>>(ema_w, out_ncs, ws_n,
                                                   out_new, out_nw);
  qwrite_kernel<<<1024, 256, 0, stream>>>(out_codes, weight, out_q);
}

// Round 3
// 759.773 us; speedup vs baseline: 4.3233x; 1.1377x over previous
//
#include <hip/hip_runtime.h>
#include <math.h>

#define NUM_K 4096
#define DIM   256
#define TLEN  1024
#define DT    (DIM * TLEN)     // 262144, per-batch z stride
#define CAP   2048             // candidate list capacity (measured E ~190/block)

typedef short bf16x8 __attribute__((ext_vector_type(8)));   // 8 bf16 in 4 VGPRs
typedef float f32x4  __attribute__((ext_vector_type(4)));

// float -> bf16, round-to-nearest-even (bit trick; inputs finite)
static __device__ __forceinline__ unsigned short f2bf(float x) {
  unsigned u = __float_as_uint(x);
  u += 0x7fffu + ((u >> 16) & 1u);
  return (unsigned short)(u >> 16);
}

static __device__ __forceinline__ f32x4 mfma16(bf16x8 a, bf16x8 b, f32x4 c) {
  return __builtin_amdgcn_mfma_f32_16x16x32_bf16(a, b, c, 0, 0, 0);
}

// ---------------- K1a: per-code norms m_c = max(||w_c||, 1e-6), numpy-bitwise ----------------
__global__ __launch_bounds__(256) void wnorm_kernel(const float* __restrict__ w,
                                                    float* __restrict__ wnorms) {
  const int k = blockIdx.x * 256 + threadIdx.x;
  const float* row = w + (size_t)k * DIM;
  float p[2];
#pragma unroll
  for (int blk = 0; blk < 2; ++blk) {
    const float* b = row + blk * 128;
    float r[8];
#pragma unroll
    for (int j = 0; j < 8; ++j) r[j] = __fmul_rn(b[j], b[j]);
    for (int i = 8; i < 128; i += 8) {
#pragma unroll
      for (int j = 0; j < 8; ++j) r[j] = __fadd_rn(r[j], __fmul_rn(b[i + j], b[i + j]));
    }
    p[blk] = __fadd_rn(__fadd_rn(__fadd_rn(r[0], r[1]), __fadd_rn(r[2], r[3])),
                       __fadd_rn(__fadd_rn(r[4], r[5]), __fadd_rn(r[6], r[7])));
  }
  wnorms[k] = fmaxf(__fsqrt_rn(__fadd_rn(p[0], p[1])), 1e-6f);
}

// ---------------- K1b: fp32 normalized codebook wnf32[k][d] = fdiv(w, m_k) ----------------
// Feeds (a) the exact rescore (contiguous, divide-free inner loop) and (b) wfrag.
// Lives in the out_new region (4096*256 floats exactly); dw_kernel overwrites it later.
__global__ __launch_bounds__(256) void wnf32_kernel(const float* __restrict__ w,
                                                    const float* __restrict__ wnorms,
                                                    float* __restrict__ wnf) {
  const int idx = blockIdx.x * 256 + threadIdx.x;   // 0..262143 (float4 units)
  const float m = wnorms[idx >> 6];
  const float4 v = *reinterpret_cast<const float4*>(w + (size_t)idx * 4);
  float4 o;
  o.x = __fdiv_rn(v.x, m); o.y = __fdiv_rn(v.y, m);
  o.z = __fdiv_rn(v.z, m); o.w = __fdiv_rn(v.w, m);
  *reinterpret_cast<float4*>(wnf + (size_t)idx * 4) = o;
}

// ---------------- K1c: bf16 B-fragment image of wn ----------------
// fragid = chunk*32 + kb*4 + jg; each fragment 1 KB = 64 lanes x 16 B:
// B[k = (lane>>4)*8 + u][col = jg*16 + (lane&15)] for mfma 16x16x32 bf16.
__global__ __launch_bounds__(256) void wfrag_kernel(const float* __restrict__ wnf,
                                                    unsigned short* __restrict__ img) {
  const int t = blockIdx.x * 256 + threadIdx.x;
  const int lane = t & 63;
  const int fragid = t >> 6;                           // 0..2047
  const int jg = fragid & 3;
  const int kb = (fragid >> 2) & 7;
  const int chunk = fragid >> 5;
  const int c  = (chunk << 6) + (jg << 4) + (lane & 15);
  const int d0 = (kb << 5) + ((lane >> 4) << 3);
  const float* src = wnf + (size_t)c * DIM + d0;
  union { bf16x8 v; unsigned short u[8]; } o;
#pragma unroll
  for (int u = 0; u < 8; ++u) o.u[u] = f2bf(src[u]);
  *reinterpret_cast<bf16x8*>(img + (size_t)fragid * 512 + lane * 8) = o.v;
}

// ---------------- K2: main fused kernel ----------------
// R3 changes: (1) full-chunk double-buffered B prefetch in registers (2x16 frags,
// launch_bounds(256,2) so the compiler has VGPR room; sched_barrier pins load issue
// ahead of the MFMA cluster) — kills the 8x serialized L2-latency stalls per chunk
// that VGPR_Count=84 exposed. (2) znT written pre-pass; exact rescore reads
// znT + wnf32 contiguously, zero divides in the chain. (3) tnorm on 128 threads.
// Verdict math unchanged (bitwise numpy fp32 seq-FMA on windowed candidates).
__global__ __launch_bounds__(256, 2) void vq_main_kernel(
    const float* __restrict__ z, const float* __restrict__ weight,
    const unsigned short* __restrict__ wimg, const float* __restrict__ wnf32,
    float* __restrict__ znT, float* __restrict__ out_codes,
    float* __restrict__ counts, float* __restrict__ loss_accum) {
  __shared__ float pp[2][64];
  __shared__ float tnorm[64];
  __shared__ float v1p[2][64];
  __shared__ float thr[64];
  __shared__ int   fidx[64];
  __shared__ int   clist[CAP];
  __shared__ float cscore[CAP];
  __shared__ int   ccount;

  const int tid  = threadIdx.x;
  const int bb   = blockIdx.x >> 4;
  const int t0   = (blockIdx.x & 15) << 6;
  const int lane = tid & 63;
  const int wv   = tid >> 6;         // wave 0..3
  const int wr   = wv >> 1;          // token half (32 tokens)
  const int wc   = wv & 1;           // code half within a 64-code chunk
  const float* zb = z + (size_t)bb * DT + t0;

  // ---- per-token norms, numpy-bitwise pairwise scheme; 128 threads (tok, 128-block) ----
  if (tid < 128) {
    const int tok = tid & 63, blk = tid >> 6;
    const float* zc = zb + tok;
    float r[8];
#pragma unroll
    for (int j = 0; j < 8; ++j) {
      const float v = zc[(size_t)(blk * 128 + j) * TLEN];
      r[j] = __fmul_rn(v, v);
    }
    for (int i = 8; i < 128; i += 8) {
#pragma unroll
      for (int j = 0; j < 8; ++j) {
        const float v = zc[(size_t)(blk * 128 + i + j) * TLEN];
        r[j] = __fadd_rn(r[j], __fmul_rn(v, v));
      }
    }
    pp[blk][tok] = __fadd_rn(__fadd_rn(__fadd_rn(r[0], r[1]), __fadd_rn(r[2], r[3])),
                             __fadd_rn(__fadd_rn(r[4], r[5]), __fadd_rn(r[6], r[7])));
  }
  if (tid == 0) ccount = 0;
  __syncthreads();
  if (tid < 64) tnorm[tid] = fmaxf(__fsqrt_rn(__fadd_rn(pp[0][tid], pp[1][tid])), 1e-6f);
  __syncthreads();

  // ---- znT = flat_z_norm (token-major), written BEFORE the passes ----
  // Thread (tok=tid&63, seg=tid>>6) writes 64 consecutive floats of its row:
  // reads coalesced across lanes; per-thread 256B contiguous writes.
  {
    const int tok = tid & 63, seg = tid >> 6;
    const float m = tnorm[tok];
    const float* zc = zb + tok;
    float* orow = znT + (size_t)((bb << 10) + t0 + tok) * DIM + (seg << 6);
#pragma unroll 4
    for (int k4 = 0; k4 < 16; ++k4) {
      float4 o;
      o.x = __fdiv_rn(zc[(size_t)((seg << 6) + (k4 << 2) + 0) * TLEN], m);
      o.y = __fdiv_rn(zc[(size_t)((seg << 6) + (k4 << 2) + 1) * TLEN], m);
      o.z = __fdiv_rn(zc[(size_t)((seg << 6) + (k4 << 2) + 2) * TLEN], m);
      o.w = __fdiv_rn(zc[(size_t)((seg << 6) + (k4 << 2) + 3) * TLEN], m);
      *reinterpret_cast<float4*>(&orow[k4 << 2]) = o;
    }
  }

  // ---- A-fragments: raw z -> bf16 in registers (staged late: short live range) ----
  bf16x8 afr[2][8];
  {
    const int tloc = (wr << 5) + (lane & 15);
    const int dr   = (lane >> 4) << 3;
#pragma unroll
    for (int i = 0; i < 2; ++i) {
      const float* zc = zb + tloc + (i << 4);
#pragma unroll
      for (int kb = 0; kb < 8; ++kb) {
        union { bf16x8 v; unsigned short u[8]; } a;
#pragma unroll
        for (int u = 0; u < 8; ++u)
          a.u[u] = f2bf(zc[(size_t)((kb << 5) + dr + u) * TLEN]);
        afr[i][kb] = a.v;
      }
    }
  }

  const unsigned short* bbase = wimg + (wc << 10) + (lane << 3);
  const f32x4 zero4 = {0.f, 0.f, 0.f, 0.f};
  const bool lc0 = (wc == 0) && ((lane & 15) == 0);   // lane carrying code chunk*64+0

#define LOADC(buf, ch) do {                                              \
    const unsigned short* p_ = bbase + ((size_t)(ch) << 14);             \
    _Pragma("unroll")                                                    \
    for (int kb_ = 0; kb_ < 8; ++kb_) {                                  \
      buf[kb_]     = *reinterpret_cast<const bf16x8*>(p_ + (kb_ << 11)); \
      buf[kb_ + 8] = *reinterpret_cast<const bf16x8*>(p_ + (kb_ << 11) + 512); \
    }                                                                    \
    __builtin_amdgcn_sched_barrier(0);                                   \
  } while (0)

#define MFMAC(buf, accv) do {                                            \
    __builtin_amdgcn_s_setprio(1);                                       \
    _Pragma("unroll")                                                    \
    for (int kb_ = 0; kb_ < 8; ++kb_) {                                  \
      accv[0][0] = mfma16(afr[0][kb_], buf[kb_],     accv[0][0]);        \
      accv[1][0] = mfma16(afr[1][kb_], buf[kb_],     accv[1][0]);        \
      accv[0][1] = mfma16(afr[0][kb_], buf[kb_ + 8], accv[0][1]);        \
      accv[1][1] = mfma16(afr[1][kb_], buf[kb_ + 8], accv[1][1]);        \
    }                                                                    \
    __builtin_amdgcn_s_setprio(0);                                       \
  } while (0)

  // ---- PASS A: approx max per token (code 0 masked), double-buffered B ----
  float v1loc[2][4];
#pragma unroll
  for (int i = 0; i < 2; ++i)
#pragma unroll
    for (int r = 0; r < 4; ++r) v1loc[i][r] = -INFINITY;
  {
    bf16x8 bA[16], bB[16];
    LOADC(bA, 0);
#pragma unroll 1
    for (int chunk = 0; chunk < 64; chunk += 2) {
      LOADC(bB, chunk + 1);
      f32x4 acc[2][2];
      acc[0][0] = zero4; acc[0][1] = zero4; acc[1][0] = zero4; acc[1][1] = zero4;
      MFMAC(bA, acc);
      {
        const bool m0 = (chunk == 0) && lc0;
#pragma unroll
        for (int i = 0; i < 2; ++i)
#pragma unroll
          for (int r = 0; r < 4; ++r) {
            float v0 = acc[i][0][r];
            if (m0) v0 = -INFINITY;
            v1loc[i][r] = fmaxf(v1loc[i][r], fmaxf(v0, acc[i][1][r]));
          }
      }
      if (chunk + 2 < 64) LOADC(bA, chunk + 2);
      f32x4 ac2[2][2];
      ac2[0][0] = zero4; ac2[0][1] = zero4; ac2[1][0] = zero4; ac2[1][1] = zero4;
      MFMAC(bB, ac2);
#pragma unroll
      for (int i = 0; i < 2; ++i)
#pragma unroll
        for (int r = 0; r < 4; ++r)
          v1loc[i][r] = fmaxf(v1loc[i][r], fmaxf(ac2[i][0][r], ac2[i][1][r]));
    }
  }
  // cross-lane reduce over the 16 code-columns, then across wc halves via LDS
#pragma unroll
  for (int i = 0; i < 2; ++i)
#pragma unroll
    for (int r = 0; r < 4; ++r) {
      float v = v1loc[i][r];
      v = fmaxf(v, __shfl_xor(v, 1));
      v = fmaxf(v, __shfl_xor(v, 2));
      v = fmaxf(v, __shfl_xor(v, 4));
      v = fmaxf(v, __shfl_xor(v, 8));
      if ((lane & 15) == 0)
        v1p[wc][(wr << 5) + (i << 4) + ((lane >> 4) << 2) + r] = v;
    }
  __syncthreads();
  // window = 0.02*m_t (>= 2.56x certified 2-sided bf16 error bound of 2*m_t*2^-8)
  if (tid < 64) thr[tid] = fmaxf(v1p[0][tid], v1p[1][tid]) - 0.02f * tnorm[tid];
  __syncthreads();

  float thrv_[2][4];
  {
    const int tb = (wr << 5) + ((lane >> 4) << 2);
#pragma unroll
    for (int i = 0; i < 2; ++i)
#pragma unroll
      for (int r = 0; r < 4; ++r) thrv_[i][r] = thr[tb + (i << 4) + r];
  }

  // ---- PASS B: bitwise-identical recompute, collect candidates >= threshold ----
  {
    bf16x8 bA[16], bB[16];
    LOADC(bA, 0);
#pragma unroll 1
    for (int chunk = 0; chunk < 64; chunk += 2) {
      LOADC(bB, chunk + 1);
      f32x4 acc[2][2];
      acc[0][0] = zero4; acc[0][1] = zero4; acc[1][0] = zero4; acc[1][1] = zero4;
      MFMAC(bA, acc);
#pragma unroll
      for (int i = 0; i < 2; ++i)
#pragma unroll
        for (int j = 0; j < 2; ++j) {
          const int c = (chunk << 6) + (wc << 5) + (j << 4) + (lane & 15);
#pragma unroll
          for (int r = 0; r < 4; ++r) {
            if (acc[i][j][r] >= thrv_[i][r] && c != 0) {
              const int pos = atomicAdd(&ccount, 1);
              if (pos < CAP)
                clist[pos] = (c << 7) | ((wr << 5) + (i << 4) + ((lane >> 4) << 2) + r);
            }
          }
        }
      if (chunk + 2 < 64) LOADC(bA, chunk + 2);
      f32x4 ac2[2][2];
      ac2[0][0] = zero4; ac2[0][1] = zero4; ac2[1][0] = zero4; ac2[1][1] = zero4;
      MFMAC(bB, ac2);
#pragma unroll
      for (int i = 0; i < 2; ++i)
#pragma unroll
        for (int j = 0; j < 2; ++j) {
          const int c = ((chunk + 1) << 6) + (wc << 5) + (j << 4) + (lane & 15);
#pragma unroll
          for (int r = 0; r < 4; ++r) {
            if (ac2[i][j][r] >= thrv_[i][r]) {
              const int pos = atomicAdd(&ccount, 1);
              if (pos < CAP)
                clist[pos] = (c << 7) | ((wr << 5) + (i << 4) + ((lane >> 4) << 2) + r);
            }
          }
        }
    }
  }
#undef LOADC
#undef MFMAC
  __syncthreads();

  // ---- exact numpy-fp32 seq-FMA rescore (znT + wnf32: contiguous, divide-free) ----
  const int ncand = min(ccount, CAP);
  for (int e = tid; e < ncand; e += 256) {
    const int pk = clist[e];
    const int tloc = pk & 127;
    const int c = pk >> 7;
    const float* za = znT + (size_t)((bb << 10) + t0 + tloc) * DIM;
    const float* wa = wnf32 + (size_t)c * DIM;
    float s = 0.f;
#pragma unroll 8
    for (int d = 0; d < DIM; ++d)
      s = fmaf(za[d], wa[d], s);
    cscore[e] = s;
  }
  __syncthreads();

  // ---- per-token select: max exact score, first occurrence (lower index) on ties ----
  if (tid < 64) {
    float best = -INFINITY; int bc = NUM_K;
    for (int e = 0; e < ncand; ++e) {
      const int pk = clist[e];
      if ((pk & 127) == tid) {
        const float s = cscore[e]; const int c = pk >> 7;
        if (s > best || (s == best && c < bc)) { best = s; bc = c; }
      }
    }
    if (bc >= NUM_K) bc = 1;   // unreachable guard
    fidx[tid] = bc;
    out_codes[bb * TLEN + t0 + tid] = (float)bc;
    atomicAdd(&counts[bc], 1.0f);
  }
  __syncthreads();

  // ---- loss phase: sum (weight[idx] - raw z)^2 ----
  {
    float lpart = 0.f;
#pragma unroll 4
    for (int r = 0; r < 16; ++r) {
      const int tk = (r << 2) + wv;           // one token per wave per round
      const int code = fidx[tk];
      const float* zc = zb + tk;
      const float4 w4 = *reinterpret_cast<const float4*>(
          weight + (size_t)code * DIM + (lane << 2));   // coalesced row read
      float4 zr4;
      zr4.x = zc[(size_t)((lane << 2) + 0) * TLEN];     // scattered, L2-hot
      zr4.y = zc[(size_t)((lane << 2) + 1) * TLEN];
      zr4.z = zc[(size_t)((lane << 2) + 2) * TLEN];
      zr4.w = zc[(size_t)((lane << 2) + 3) * TLEN];
      const float dx = w4.x - zr4.x, dy = w4.y - zr4.y;
      const float dz = w4.z - zr4.z, dw_ = w4.w - zr4.w;
      lpart = fmaf(dx, dx, lpart); lpart = fmaf(dy, dy, lpart);
      lpart = fmaf(dz, dz, lpart); lpart = fmaf(dw_, dw_, lpart);
    }
#pragma unroll
    for (int off = 32; off; off >>= 1) lpart += __shfl_down(lpart, off, 64);
    if (lane == 0) atomicAdd(loss_accum, lpart);
  }
}

// ---------------- K3: new_cs, n, loss scalar + exclusive scan of counts ----------------
__global__ __launch_bounds__(256) void finalize_cs_kernel(
    const float* __restrict__ counts, const float* __restrict__ ema_cs,
    float* __restrict__ out_ncs, float* __restrict__ ws_n,
    const float* __restrict__ loss_accum, float* __restrict__ out_loss,
    int* __restrict__ offsets) {
  __shared__ float redf[4];
  __shared__ int   redi[4];
  const int tid = threadIdx.x;
  const int lane = tid & 63, wv = tid >> 6;
  const int base = tid << 4;
  int cloc[16]; int csum = 0; float fsum = 0.f;
#pragma unroll
  for (int j = 0; j < 16; ++j) {
    const int k = base + j;
    const float cf = counts[k];
    const float v = (k == 0) ? 0.f : 0.99f * ema_cs[k] + 0.01f * cf;
    out_ncs[k] = v; fsum += v;
    cloc[j] = csum; csum += (int)cf;
  }
  int inc = csum;                    // wave-inclusive scan
#pragma unroll
  for (int off = 1; off < 64; off <<= 1) {
    const int t = __shfl_up(inc, off, 64);
    if (lane >= off) inc += t;
  }
  float fs = fsum;
#pragma unroll
  for (int off = 32; off; off >>= 1) fs += __shfl_down(fs, off, 64);
  if (lane == 63) redi[wv] = inc;
  if (lane == 0)  redf[wv] = fs;
  __syncthreads();
  int wbase = 0;
#pragma unroll
  for (int w = 0; w < 4; ++w) wbase += (w < wv) ? redi[w] : 0;
  const int tbase = wbase + inc - csum;   // exclusive base for this thread
#pragma unroll
  for (int j = 0; j < 16; ++j) offsets[base + j] = tbase + cloc[j];
  if (tid == 0) {
    ws_n[0] = redf[0] + redf[1] + redf[2] + redf[3];
    out_loss[0] = 0.25f * loss_accum[0] / 16777216.0f;
  }
}

// ---------------- K3b: scatter token ids into per-code buckets ----------------
__global__ __launch_bounds__(256) void scatter_kernel(
    const float* __restrict__ codes, const int* __restrict__ offsets,
    int* __restrict__ cursor, int* __restrict__ bucket) {
  const int g = blockIdx.x * 256 + threadIdx.x;
  const int c = (int)codes[g];
  const int pos = atomicAdd(&cursor[c], 1);
  bucket[offsets[c] + pos] = g;
}

// ---------------- K3c: dw[k] = sum of znT rows in bucket k (coalesced, no atomics) ----------------
__global__ __launch_bounds__(256) void dw_kernel(
    const float* __restrict__ znT, const float* __restrict__ counts,
    const int* __restrict__ offsets, const int* __restrict__ bucket,
    float* __restrict__ dw) {
  const int c = blockIdx.x;
  const int cnt = (int)counts[c];
  const int off = offsets[c];
  const int tid = threadIdx.x;
  float acc = 0.f;
  for (int i = 0; i < cnt; ++i) {
    const int g = bucket[off + i];
    acc += znT[(size_t)g * DIM + tid];     // 1 KB coalesced row read
  }
  dw[(size_t)c * DIM + tid] = acc;         // writes every row (overwrites wnf32)
}

// ---------------- K4: new_ema_w (in place over dw) + new_weight ----------------
__global__ __launch_bounds__(256) void finalize_w_kernel(
    const float* __restrict__ ema_w, const float* __restrict__ ncs,
    const float* __restrict__ ws_n, float* __restrict__ new_ema_w,
    float* __restrict__ new_weight) {
  const int wid  = threadIdx.x >> 6;
  const int lane = threadIdx.x & 63;
  const int k    = (blockIdx.x << 2) + wid;
  const float n  = ws_n[0];
  const float cs = (ncs[k] + 1e-5f) / (n + 4096.0f * 1e-5f) * n;
  const float* erow = ema_w + k * DIM;
  float* nrow = new_ema_w + k * DIM;
  float* wrow = new_weight + k * DIM;
  const int d0 = lane << 2;
  float u[4]; float ss = 0.f;
#pragma unroll
  for (int j = 0; j < 4; ++j) {
    const float dwv = nrow[d0 + j];
    const float val = (k == 0) ? 0.f : 0.99f * erow[d0 + j] + 0.01f * dwv;
    nrow[d0 + j] = val;
    const float uu = val / cs;
    u[j] = uu;
    ss = fmaf(uu, uu, ss);
  }
#pragma unroll
  for (int off = 32; off; off >>= 1) ss += __shfl_xor(ss, off, 64);
  const float m = fmaxf(sqrtf(ss), 1e-6f);
#pragma unroll
  for (int j = 0; j < 4; ++j) wrow[d0 + j] = u[j] / m;
}

// ---------------- K5: final quantized = weight[idx], overwrites znT region ----------------
__global__ __launch_bounds__(256) void qwrite_kernel(
    const float* __restrict__ codes, const float* __restrict__ weight,
    float* __restrict__ out_q) {
  const int bb = blockIdx.x >> 4;
  const int t0 = (blockIdx.x & 15) << 6;
  const int ln = threadIdx.x & 63, qv = threadIdx.x >> 6;
  const int code = (int)codes[bb * TLEN + t0 + ln];
  const float* wrow = weight + (size_t)code * DIM;
  float* qb = out_q + (size_t)bb * DT + t0 + ln;
#pragma unroll 4
  for (int dd = 0; dd < 64; ++dd) {
    const int d = (qv << 6) + dd;
    qb[(size_t)d * TLEN] = wrow[d];        // gather L2-hot, store coalesced
  }
}

extern "C" void kernel_launch(void* const* d_in, const int* in_sizes, int n_in,
                              void* d_out, int out_size, void* d_ws, size_t ws_size,
                              hipStream_t stream) {
  const float* z      = (const float*)d_in[0];   // [64,256,1024]
  const float* weight = (const float*)d_in[1];   // [4096,256]
  const float* ema_cs = (const float*)d_in[2];   // [4096]
  const float* ema_w  = (const float*)d_in[3];   // [4096,256]

  float* out = (float*)d_out;
  // output layout (floats): quantized | loss | codes | new_weight | new_cs | new_ema_w
  float* out_q     = out;                    // 16777216 (holds znT until qwrite)
  float* out_loss  = out + 16777216;         // 1
  float* out_codes = out + 16777217;         // 65536
  float* out_nw    = out + 16842753;         // 1048576 (temp: wimg/bucket/offsets/cursor)
  float* out_ncs   = out + 17891329;         // 4096
  float* out_new   = out + 17895425;         // 1048576 (wnf32 -> dw, overwritten in order)

  float* counts     = (float*)d_ws;          // 4096 floats
  float* loss_accum = counts + 4096;         // 1
  float* ws_n       = counts + 4097;         // 1
  float* wnorms     = counts + 4352;         // 4096 floats, 16B-aligned

  // Scratch aliased into dead d_out regions:
  // wimg: 2 MiB bf16 image at out_nw+3 (16B-aligned); dead after vq_main.
  // bucket overlays the dead image; offsets/cursor sit past it.
  // wnf32 = out_new region (4096*256 floats exactly); dead after vq_main,
  // then overwritten by dw_kernel, then finalize_w in place.
  unsigned short* wimg = (unsigned short*)(out_nw + 3);
  int* bucket  = (int*)(out_nw + 3);         // 65536 ints (aliases dead wimg)
  int* offsets = (int*)(out_nw + 524292);    // 4096 ints
  int* cursor  = (int*)(out_nw + 528388);    // 4096 ints
  float* wnf32 = out_new;

  hipMemsetAsync(d_ws, 0, 4098 * sizeof(float), stream);
  hipMemsetAsync(cursor, 0, 4096 * sizeof(int), stream);

  wnorm_kernel<<<16, 256, 0, stream>>>(weight, wnorms);
  wnf32_kernel<<<1024, 256, 0, stream>>>(weight, wnorms, wnf32);
  wfrag_kernel<<<512, 256, 0, stream>>>(wnf32, wimg);
  vq_main_kernel<<<1024, 256, 0, stream>>>(z, weight, wimg, wnf32, out_q /*znT*/,
                                           out_codes, counts, loss_accum);
  finalize_cs_kernel<<<1, 256, 0, stream>>>(counts, ema_cs, out_ncs, ws_n,
                                            loss_accum, out_loss, offsets);
  scatter_kernel<<<256, 256, 0, stream>>>(out_codes, offsets, cursor, bucket);
  dw_kernel<<<NUM_K, 256, 0, stream>>>(out_q /*znT*/, counts, offsets, bucket, out_new);
  finalize_w_kernel<<<NUM_K / 4, 256, 0, stream>>>(ema_w, out_ncs, ws_n,
                                                   out_new, out_nw);
  qwrite_kernel<<<1024, 256, 0, stream>>>(out_codes, weight, out_q);
}